// Round 13
// baseline (391.569 us; speedup 1.0000x reference)
//
#include <hip/hip_runtime.h>
#include <math.h>

#define Bq 8
#define Mq 8192
#define Dq 1024
#define Nq 128
#define Fq 4096

typedef __bf16 bf16x8 __attribute__((ext_vector_type(8)));
typedef float f32x4 __attribute__((ext_vector_type(4)));
union P4 { __bf16 h[4]; unsigned long long u; };
union H4 { short4 v; _Float16 h[4]; };
union B8 { int4 v; __bf16 h[8]; };
union U4 { ushort4 v; __bf16 h[4]; };

// swizzled LDS offsets: XOR byte-bits 4-6 with row&7
__device__ __forceinline__ int swz128(int row, int bcol) {  // rows of 64 bf16 (128 B)
  return row * 128 + (bcol ^ ((row & 7) << 4));
}
__device__ __forceinline__ int swz256(int row, int bcol) {  // rows of 128 bf16 (256 B)
  return row * 256 + (bcol ^ ((row & 7) << 4));
}
// xi-local swizzle: folds row>>3 so 4-consecutive-row packed b128 writes spread banks
__device__ __forceinline__ int swzX(int row, int bcol) {
  return row * 128 + (bcol ^ ((((row & 7) ^ ((row >> 3) & 7))) << 4));
}

// ---------------- phi [1024 d][128 n] fp32 -> phiT [128 n][1024 d] bf16 ----------------
__global__ __launch_bounds__(256) void phi_conv(const float* __restrict__ src,
                                                __bf16* __restrict__ dst)
{
  int idx = blockIdx.x * 256 + threadIdx.x;   // 131072
  int d = idx >> 7, n = idx & 127;
  dst[(long)n * Dq + d] = (__bf16)src[idx];
}

// ---------------- transposing weight convert: src [R][C] fp32 -> dst [C][R] bf16 ----------------
__global__ __launch_bounds__(256) void wconvT(const float* __restrict__ src,
                                              __bf16* __restrict__ dst, int R, int C)
{
  __shared__ __bf16 tile[64][66];
  int c0 = blockIdx.x * 64, r0 = blockIdx.y * 64;
  int t = threadIdx.x;
  int row = t >> 2, cq = (t & 3) * 16;
  const float* S = src + (long)(r0 + row) * C + c0 + cq;
  #pragma unroll
  for (int q = 0; q < 4; ++q) {
    float4 v = *(const float4*)(S + q * 4);
    tile[cq + q * 4 + 0][row] = (__bf16)v.x;
    tile[cq + q * 4 + 1][row] = (__bf16)v.y;
    tile[cq + q * 4 + 2][row] = (__bf16)v.z;
    tile[cq + q * 4 + 3][row] = (__bf16)v.w;
  }
  __syncthreads();
  __bf16* D = dst + (long)(c0 + row) * R + r0 + cq;
  B8 o0, o1;
  #pragma unroll
  for (int e = 0; e < 8; ++e) { o0.h[e] = tile[row][cq + e]; o1.h[e] = tile[row][cq + 8 + e]; }
  *(int4*)(D) = o0.v;
  *(int4*)(D + 8) = o1.v;
}

// ---------------- logits = X @ phi via bf16 MFMA, BK=128 (half the barriers, 512B row spans) ----------------
// WXB: also emit xb bf16 [b][m][d]. Epilogue: cbuf row-softmax, eT = exp (transposed).
template<bool WXB>
__global__ __launch_bounds__(256) void logits_mfma(
    const float* __restrict__ x, const __bf16* __restrict__ phiT,
    __bf16* __restrict__ eT, __bf16* __restrict__ cbuf, __bf16* __restrict__ xb)
{
  __shared__ __align__(16) char sA[32768];  // x tile  [128 m][128 k] bf16
  __shared__ __align__(16) char sP[32768];  // phiT    [128 n][128 k] bf16
  int mt = blockIdx.x, b = blockIdx.y;
  int m0 = mt * 128;
  int t = threadIdx.x;
  int ar5 = t >> 5, ac5 = t & 31;           // x staging: 8 row-groups x 32 lanes
  int prow = t >> 1, pc8 = (t & 1) * 8;     // phi staging
  int w = t >> 6, l = t & 63, la = l & 15, lb = l >> 4;

  f32x4 zero = {0.f, 0.f, 0.f, 0.f};
  f32x4 acc[2][8];
  for (int i = 0; i < 2; ++i) for (int j = 0; j < 8; ++j) acc[i][j] = zero;

  for (int k0 = 0; k0 < Dq; k0 += 128) {
    #pragma unroll
    for (int i = 0; i < 16; ++i) {
      int row = ar5 + 8 * i;
      const float* src = x + ((long)b * Mq + m0 + row) * Dq + k0 + ac5 * 4;
      float4 v = *(const float4*)src;
      P4 p;
      p.h[0] = (__bf16)v.x; p.h[1] = (__bf16)v.y;
      p.h[2] = (__bf16)v.z; p.h[3] = (__bf16)v.w;
      *(unsigned long long*)(sA + swz256(row, ac5 * 8)) = p.u;
      if (WXB)
        *(unsigned long long*)(xb + ((long)b * Mq + m0 + row) * Dq + k0 + ac5 * 4) = p.u;
    }
    {
      const __bf16* Pp = phiT + (long)prow * Dq + k0;
      #pragma unroll
      for (int q = 0; q < 8; ++q)
        *(int4*)(sP + swz256(prow, (pc8 + q) * 16)) = *(const int4*)(Pp + (pc8 + q) * 8);
    }
    __syncthreads();
    #pragma unroll
    for (int sub = 0; sub < 4; ++sub) {
      int mbyte = sub * 64 + lb * 16;
      bf16x8 af0 = *(const bf16x8*)(sA + swz256(w * 32 + la, mbyte));
      bf16x8 af1 = *(const bf16x8*)(sA + swz256(w * 32 + 16 + la, mbyte));
      bf16x8 bv[8];
      #pragma unroll
      for (int j = 0; j < 8; ++j)
        bv[j] = *(const bf16x8*)(sP + swz256(j * 16 + la, mbyte));
      #pragma unroll
      for (int j = 0; j < 8; ++j) {
        acc[0][j] = __builtin_amdgcn_mfma_f32_16x16x32_bf16(af0, bv[j], acc[0][j], 0, 0, 0);
        acc[1][j] = __builtin_amdgcn_mfma_f32_16x16x32_bf16(af1, bv[j], acc[1][j], 0, 0, 0);
      }
    }
    __syncthreads();
  }
  // per-row (m) softmax denominators over 128 n (max-free, |l| <~ 6)
  float inv[2][4];
  #pragma unroll
  for (int i = 0; i < 2; ++i)
    #pragma unroll
    for (int r = 0; r < 4; ++r) {
      float s = 0.f;
      #pragma unroll
      for (int j = 0; j < 8; ++j) s += __expf(acc[i][j][r]);
      s += __shfl_xor(s, 1); s += __shfl_xor(s, 2);
      s += __shfl_xor(s, 4); s += __shfl_xor(s, 8);
      inv[i][r] = 1.0f / s;
    }
  __bf16* Cb = cbuf + ((long)b * Mq + m0) * Nq;
  __bf16* Eb = eT + (long)b * Nq * Mq + m0;
  #pragma unroll
  for (int i = 0; i < 2; ++i)
    #pragma unroll
    for (int j = 0; j < 8; ++j) {
      P4 p;
      #pragma unroll
      for (int r = 0; r < 4; ++r) {
        int row = w * 32 + i * 16 + lb * 4 + r;
        float e = __expf(acc[i][j][r]);
        p.h[r] = (__bf16)e;
        Cb[(long)row * Nq + j * 16 + la] = (__bf16)(e * inv[i][r]);
      }
      *(unsigned long long*)(Eb + (long)(j * 16 + la) * Mq + w * 32 + i * 16 + lb * 4) = p.u;
    }
}

// ---------------- cinv[b*128+n] = 1 / rowsum(eT) ----------------
__global__ __launch_bounds__(256) void colsum_rows(const __bf16* __restrict__ eT,
                                                   float* __restrict__ cinv)
{
  __shared__ float red[4];
  int r = blockIdx.x;
  int t = threadIdx.x;
  const __bf16* p = eT + (long)r * Mq;
  float s = 0.f;
  #pragma unroll
  for (int k = 0; k < 4; ++k) {
    B8 v; v.v = *(const int4*)(p + t * 8 + k * 2048);
    #pragma unroll
    for (int e = 0; e < 8; ++e) s += (float)v.h[e];
  }
  #pragma unroll
  for (int off = 32; off >= 1; off >>= 1) s += __shfl_down(s, off);
  if ((t & 63) == 0) red[t >> 6] = s;
  __syncthreads();
  if (t == 0) cinv[r] = 1.0f / (red[0] + red[1] + red[2] + red[3]);
}

// ---------------- xi partials from xb bf16: 128 n x 128 d per block, kc of 8 ----------------
__global__ __launch_bounds__(256) void xi_mfma_xb(
    const __bf16* __restrict__ eT, const __bf16* __restrict__ xb,
    _Float16* __restrict__ part)
{
  __shared__ __align__(16) char sD[16384];  // eT tile [128 n][64 m]
  __shared__ __align__(16) char sX[16384];  // xb^T tile [128 d][64 m]
  int lin = blockIdx.x;
  int wk = (lin & 7) * 64 + (lin >> 3);     // same-eT-chunk blocks -> same XCD
  int dts = wk & 7, kc = (wk >> 3) & 7, b = wk >> 6;
  int d0 = dts * 128;
  int t = threadIdx.x;
  int w = t >> 6, l = t & 63, la = l & 15, lb = l >> 4;
  int arow = t >> 1, ahalf = t & 1;
  const __bf16* Ep0 = eT + ((long)b * Nq + arow) * Mq + kc * 1024 + ahalf * 32;
  int bmb = (w * 2 + (l >> 5)) * 8;
  int bd  = (l & 31) * 4;
  const __bf16* Xp0 = xb + ((long)b * Mq + kc * 1024 + bmb) * Dq + d0 + bd;

  f32x4 zero = {0.f, 0.f, 0.f, 0.f};
  f32x4 acc[2][8];
  for (int i = 0; i < 2; ++i) for (int j = 0; j < 8; ++j) acc[i][j] = zero;

  int4 ar[4];
  U4 br[8];
  #pragma unroll
  for (int q = 0; q < 4; ++q) ar[q] = *(const int4*)(Ep0 + q * 8);
  #pragma unroll
  for (int k = 0; k < 8; ++k) br[k].v = *(const ushort4*)(Xp0 + (long)k * Dq);
  #pragma unroll
  for (int q = 0; q < 4; ++q) *(int4*)(sD + swzX(arow, ahalf * 64 + q * 16)) = ar[q];
  #pragma unroll
  for (int q = 0; q < 4; ++q) {
    B8 o;
    #pragma unroll
    for (int k = 0; k < 8; ++k) o.h[k] = br[k].h[q];
    *(int4*)(sX + swzX(bd + q, 2 * bmb)) = o.v;
  }

  for (int it = 0; it < 16; ++it) {
    __syncthreads();
    if (it < 15) {
      #pragma unroll
      for (int q = 0; q < 4; ++q) ar[q] = *(const int4*)(Ep0 + (it + 1) * 64 + q * 8);
      #pragma unroll
      for (int k = 0; k < 8; ++k)
        br[k].v = *(const ushort4*)(Xp0 + ((long)(it + 1) * 64 + k) * Dq);
    }
    #pragma unroll
    for (int sub = 0; sub < 2; ++sub) {
      int mbyte = sub * 64 + lb * 16;
      bf16x8 af0 = *(const bf16x8*)(sD + swzX(w * 32 + la, mbyte));
      bf16x8 af1 = *(const bf16x8*)(sD + swzX(w * 32 + 16 + la, mbyte));
      #pragma unroll
      for (int j = 0; j < 8; ++j) {
        bf16x8 bv = *(const bf16x8*)(sX + swzX(j * 16 + la, mbyte));
        acc[0][j] = __builtin_amdgcn_mfma_f32_16x16x32_bf16(af0, bv, acc[0][j], 0, 0, 0);
        acc[1][j] = __builtin_amdgcn_mfma_f32_16x16x32_bf16(af1, bv, acc[1][j], 0, 0, 0);
      }
    }
    __syncthreads();
    if (it < 15) {
      #pragma unroll
      for (int q = 0; q < 4; ++q) *(int4*)(sD + swzX(arow, ahalf * 64 + q * 16)) = ar[q];
      #pragma unroll
      for (int q = 0; q < 4; ++q) {
        B8 o;
        #pragma unroll
        for (int k = 0; k < 8; ++k) o.h[k] = br[k].h[q];
        *(int4*)(sX + swzX(bd + q, 2 * bmb)) = o.v;
      }
    }
  }
  _Float16* P = part + (((long)kc * Bq + b) * 8 + dts) * 16384;
  #pragma unroll
  for (int i = 0; i < 2; ++i)
    #pragma unroll
    for (int j = 0; j < 8; ++j) {
      H4 o;
      #pragma unroll
      for (int r = 0; r < 4; ++r) o.h[r] = (_Float16)acc[i][j][r];
      *(short4*)(P + ((w * 16 + i * 8 + j) * 64 + l) * 4) = o.v;
    }
}

// ---------------- xi fallback (fp32 x) for small ws ----------------
__global__ __launch_bounds__(256) void xi_mfma_f32(
    const __bf16* __restrict__ eT, const float* __restrict__ x,
    _Float16* __restrict__ part)
{
  __shared__ __align__(16) char sD[16384];
  __shared__ __align__(16) char sX[16384];
  int lin = blockIdx.x;
  int wk = (lin & 7) * 64 + (lin >> 3);
  int dts = wk & 7, kc = (wk >> 3) & 7, b = wk >> 6;
  int d0 = dts * 128;
  int t = threadIdx.x;
  int w = t >> 6, l = t & 63, la = l & 15, lb = l >> 4;
  int arow = t >> 1, ahalf = t & 1;
  const __bf16* Ep0 = eT + ((long)b * Nq + arow) * Mq + kc * 1024 + ahalf * 32;
  int bmb = (w * 2 + (l >> 5)) * 8;
  int bd  = (l & 31) * 4;
  const float* Xp0 = x + ((long)b * Mq + kc * 1024 + bmb) * Dq + d0 + bd;

  f32x4 zero = {0.f, 0.f, 0.f, 0.f};
  f32x4 acc[2][8];
  for (int i = 0; i < 2; ++i) for (int j = 0; j < 8; ++j) acc[i][j] = zero;

  int4 ar[4];
  float br[8][4];
  #pragma unroll
  for (int q = 0; q < 4; ++q) ar[q] = *(const int4*)(Ep0 + q * 8);
  #pragma unroll
  for (int k = 0; k < 8; ++k) *(float4*)br[k] = *(const float4*)(Xp0 + (long)k * Dq);
  #pragma unroll
  for (int q = 0; q < 4; ++q) *(int4*)(sD + swzX(arow, ahalf * 64 + q * 16)) = ar[q];
  #pragma unroll
  for (int q = 0; q < 4; ++q) {
    B8 o;
    #pragma unroll
    for (int k = 0; k < 8; ++k) o.h[k] = (__bf16)br[k][q];
    *(int4*)(sX + swzX(bd + q, 2 * bmb)) = o.v;
  }
  for (int it = 0; it < 16; ++it) {
    __syncthreads();
    if (it < 15) {
      #pragma unroll
      for (int q = 0; q < 4; ++q) ar[q] = *(const int4*)(Ep0 + (it + 1) * 64 + q * 8);
      #pragma unroll
      for (int k = 0; k < 8; ++k)
        *(float4*)br[k] = *(const float4*)(Xp0 + ((long)(it + 1) * 64 + k) * Dq);
    }
    #pragma unroll
    for (int sub = 0; sub < 2; ++sub) {
      int mbyte = sub * 64 + lb * 16;
      bf16x8 af0 = *(const bf16x8*)(sD + swzX(w * 32 + la, mbyte));
      bf16x8 af1 = *(const bf16x8*)(sD + swzX(w * 32 + 16 + la, mbyte));
      #pragma unroll
      for (int j = 0; j < 8; ++j) {
        bf16x8 bv = *(const bf16x8*)(sX + swzX(j * 16 + la, mbyte));
        acc[0][j] = __builtin_amdgcn_mfma_f32_16x16x32_bf16(af0, bv, acc[0][j], 0, 0, 0);
        acc[1][j] = __builtin_amdgcn_mfma_f32_16x16x32_bf16(af1, bv, acc[1][j], 0, 0, 0);
      }
    }
    __syncthreads();
    if (it < 15) {
      #pragma unroll
      for (int q = 0; q < 4; ++q) *(int4*)(sD + swzX(arow, ahalf * 64 + q * 16)) = ar[q];
      #pragma unroll
      for (int q = 0; q < 4; ++q) {
        B8 o;
        #pragma unroll
        for (int k = 0; k < 8; ++k) o.h[k] = (__bf16)br[k][q];
        *(int4*)(sX + swzX(bd + q, 2 * bmb)) = o.v;
      }
    }
  }
  _Float16* P = part + (((long)kc * Bq + b) * 8 + dts) * 16384;
  #pragma unroll
  for (int i = 0; i < 2; ++i)
    #pragma unroll
    for (int j = 0; j < 8; ++j) {
      H4 o;
      #pragma unroll
      for (int r = 0; r < 4; ++r) o.h[r] = (_Float16)acc[i][j][r];
      *(short4*)(P + ((w * 16 + i * 8 + j) * 64 + l) * 4) = o.v;
    }
}

// ---------------- xi reduce (fragment layout): xib[n][d] = bf16(cinv * sum_kc) ----------------
__global__ __launch_bounds__(256) void xi_reduce(const _Float16* __restrict__ part,
    const float* __restrict__ cinv, __bf16* __restrict__ xib)
{
  int s = blockIdx.x * 256 + threadIdx.x;   // 262144 fragment slots (4 vals each)
  int l = s & 63, j = (s >> 6) & 7, i = (s >> 9) & 1;
  int w = (s >> 10) & 3, dts = (s >> 12) & 7, b = s >> 15;
  const _Float16* p = part + ((long)b * 8 + dts) * 16384 + ((w * 16 + i * 8 + j) * 64 + l) * 4;
  float sum[4] = {};
  #pragma unroll
  for (int kc = 0; kc < 8; ++kc) {
    H4 v; v.v = *(const short4*)(p + (long)kc * 1048576);
    #pragma unroll
    for (int r = 0; r < 4; ++r) sum[r] += (float)v.h[r];
  }
  int lb = l >> 4, la = l & 15;
  int nbase = w * 32 + i * 16 + lb * 4;
  int d = dts * 128 + j * 16 + la;
  #pragma unroll
  for (int r = 0; r < 4; ++r) {
    int n = b * 128 + nbase + r;
    xib[(long)n * Dq + d] = (__bf16)(sum[r] * cinv[n]);
  }
}

// ---------------- bf16 MFMA GEMM, BOTH operands k-contiguous: A[m][k], BT[n][k] ----------------
template<int EPI, typename OT>
__global__ __launch_bounds__(256) void gemm_tt(const __bf16* __restrict__ A,
    const __bf16* __restrict__ BT, const float* __restrict__ bias,
    OT* __restrict__ C, int lda, int ldb, int ldc, int kLen, long strideCz)
{
  __shared__ __align__(16) char sA[16384];
  __shared__ __align__(16) char sB[16384];
  int m0 = blockIdx.x * 128, n0 = blockIdx.y * 128;
  int kbase = blockIdx.z * kLen;
  C += (long)blockIdx.z * strideCz;
  int t = threadIdx.x;
  int w = t >> 6, l = t & 63, la = l & 15, lb = l >> 4;

  f32x4 zero = {0.f, 0.f, 0.f, 0.f};
  f32x4 acc[2][8];
  for (int i = 0; i < 2; ++i) for (int j = 0; j < 8; ++j) acc[i][j] = zero;

  for (int kt = 0; kt < kLen; kt += 64) {
    int kp = kbase + kt;
    #pragma unroll
    for (int s = 0; s < 4; ++s) {
      int idx = t + 256 * s;
      int row = idx >> 3, c8 = idx & 7;
      *(int4*)(sA + swz128(row, c8 * 16)) =
          *(const int4*)(A + (long)(m0 + row) * lda + kp + c8 * 8);
      *(int4*)(sB + swz128(row, c8 * 16)) =
          *(const int4*)(BT + (long)(n0 + row) * ldb + kp + c8 * 8);
    }
    __syncthreads();
    #pragma unroll
    for (int sub = 0; sub < 2; ++sub) {
      int mbyte = sub * 64 + lb * 16;
      bf16x8 af0 = *(const bf16x8*)(sA + swz128(w * 32 + la, mbyte));
      bf16x8 af1 = *(const bf16x8*)(sA + swz128(w * 32 + 16 + la, mbyte));
      bf16x8 bv[8];
      #pragma unroll
      for (int j = 0; j < 8; ++j)
        bv[j] = *(const bf16x8*)(sB + swz128(j * 16 + la, mbyte));
      #pragma unroll
      for (int j = 0; j < 8; ++j) {
        acc[0][j] = __builtin_amdgcn_mfma_f32_16x16x32_bf16(af0, bv[j], acc[0][j], 0, 0, 0);
        acc[1][j] = __builtin_amdgcn_mfma_f32_16x16x32_bf16(af1, bv[j], acc[1][j], 0, 0, 0);
      }
    }
    __syncthreads();
  }
  #pragma unroll
  for (int i = 0; i < 2; ++i)
    #pragma unroll
    for (int j = 0; j < 8; ++j)
      #pragma unroll
      for (int r = 0; r < 4; ++r) {
        int row = m0 + w * 32 + i * 16 + lb * 4 + r;
        int colg = n0 + j * 16 + la;
        float v = acc[i][j][r];
        if (EPI == 2) {
          v += bias[colg];
          v = 0.5f * v * (1.0f + erff(v * 0.70710678118654752f));
        }
        C[(long)row * ldc + colg] = (OT)v;
      }
}

// ---------------- G2 reduce: yiT[b][d][n] = bf16(sum_kc part + b2[d]) ----------------
__global__ __launch_bounds__(256) void g2_reduce(const float* __restrict__ part,
    const float* __restrict__ b2, __bf16* __restrict__ yiT)
{
  long idx = (long)blockIdx.x * 256 + threadIdx.x;
  int row = (int)(idx >> 10);
  int d = (int)(idx & 1023);
  float s = part[idx] + part[idx + 1048576] + part[idx + 2097152] + part[idx + 3145728] + b2[d];
  int b = row >> 7, n = row & 127;
  yiT[((long)b * Dq + d) * Nq + n] = (__bf16)s;
}

// ---------------- combine: y[b,m,d] = sum_n cbuf[m,n] * yiT[d,n] ----------------
// LDS-staged y epilogue: acc -> 64KB LDS (xor-swizzled) -> 512B-run coalesced stores
__global__ __launch_bounds__(256) void combine_mfma(const __bf16* __restrict__ cbuf,
    const __bf16* __restrict__ yiT, float* __restrict__ y)
{
  __shared__ __align__(16) char smem[65536];
  char* sC = smem;            // c  [128 m][128 n]
  char* sY = smem + 32768;    // yi [128 d][128 n]
  int lin = blockIdx.x;
  int wk = (lin & 7) * 512 + (lin >> 3);
  int dt = wk & 7, mt = (wk >> 3) & 63, b = wk >> 9;
  int m0 = mt * 128, d0 = dt * 128;
  int t = threadIdx.x;
  #pragma unroll
  for (int s = 0; s < 8; ++s) {
    int idx = t + 256 * s;
    int row = idx >> 4, c16 = idx & 15;
    *(int4*)(sC + swz256(row, c16 * 16)) =
        *(const int4*)(cbuf + ((long)b * Mq + m0 + row) * Nq + c16 * 8);
    *(int4*)(sY + swz256(row, c16 * 16)) =
        *(const int4*)(yiT + ((long)b * Dq + d0 + row) * Nq + c16 * 8);
  }
  __syncthreads();
  int w = t >> 6, l = t & 63, la = l & 15, lb = l >> 4;
  f32x4 zero = {0.f, 0.f, 0.f, 0.f};
  f32x4 acc[2][8];
  for (int i = 0; i < 2; ++i) for (int j = 0; j < 8; ++j) acc[i][j] = zero;
  #pragma unroll
  for (int sub = 0; sub < 4; ++sub) {
    int mbyte = sub * 64 + lb * 16;
    bf16x8 af0 = *(const bf16x8*)(sC + swz256(w * 32 + la, mbyte));
    bf16x8 af1 = *(const bf16x8*)(sC + swz256(w * 32 + 16 + la, mbyte));
    #pragma unroll
    for (int j = 0; j < 8; ++j) {
      bf16x8 bv = *(const bf16x8*)(sY + swz256(j * 16 + la, mbyte));
      acc[0][j] = __builtin_amdgcn_mfma_f32_16x16x32_bf16(af0, bv, acc[0][j], 0, 0, 0);
      acc[1][j] = __builtin_amdgcn_mfma_f32_16x16x32_bf16(af1, bv, acc[1][j], 0, 0, 0);
    }
  }
  // stage acc through LDS for long-run y stores
  __syncthreads();
  float* sF = (float*)smem;   // y tile [128 m][128 d], col ^ (((row>>2)&3)<<3)
  #pragma unroll
  for (int i = 0; i < 2; ++i)
    #pragma unroll
    for (int j = 0; j < 8; ++j)
      #pragma unroll
      for (int r = 0; r < 4; ++r) {
        int row = w * 32 + i * 16 + lb * 4 + r;
        sF[row * 128 + ((j * 16 + la) ^ (lb << 3))] = acc[i][j][r];
      }
  __syncthreads();
  int orow = t >> 5, oc = (t & 31) * 4;   // 8 rows/pass x 32 lanes -> 512B runs
  #pragma unroll
  for (int p = 0; p < 16; ++p) {
    int row = orow + 8 * p;
    int xorv = ((row >> 2) & 3) << 3;
    float4 v = *(const float4*)&sF[row * 128 + (oc ^ xorv)];
    *(float4*)(y + ((long)b * Mq + m0 + row) * Dq + d0 + oc) = v;
  }
}

extern "C" void kernel_launch(void* const* d_in, const int* in_sizes, int n_in,
                              void* d_out, int out_size, void* d_ws, size_t ws_size,
                              hipStream_t stream) {
  const float* x   = (const float*)d_in[0];
  const float* phi = (const float*)d_in[1];
  const float* W1  = (const float*)d_in[2];
  const float* b1  = (const float*)d_in[3];
  const float* W2  = (const float*)d_in[4];
  const float* b2  = (const float*)d_in[5];
  float* y = (float*)d_out;

  char* W = (char*)d_ws;
  __bf16*   cbuf   = (__bf16*)W;                      // 16 MB
  __bf16*   eT     = (__bf16*)(W + 16777216);         // 16 MB  [b][n][m]
  __bf16*   h      = eT;                              // aliases eT (dead after xi)
  _Float16* part   = (_Float16*)(W + 33554432);       // 16 MB fp16 fragment-layout
  float*    g2part = (float*)(W + 33554432);          // aliases part (dead after xi_reduce)
  __bf16*   W1T    = (__bf16*)(W + 50331648);         // 8 MB  [f][d]
  __bf16*   W2T    = (__bf16*)(W + 58720256);         // 8 MB  [d][f]
  __bf16*   xib    = (__bf16*)(W + 67108864);         // 2 MB
  __bf16*   yiT    = (__bf16*)(W + 69206016);         // 2 MB
  float*    cinv   = (float*)(W + 71303168);          // 4 KB
  __bf16*   phiT   = (__bf16*)(W + 72351744);         // 256 KB [n][d]
  __bf16*   xb     = (__bf16*)(W + 73400320);         // 128 MB [b][m][d] bf16 (optional)
  bool big = ws_size >= 207618048ull;                 // 70 MB base + 128 MB xb

  // 0) weights -> transposed bf16; phi -> transposed bf16
  wconvT<<<dim3(Fq / 64, Dq / 64), 256, 0, stream>>>(W1, W1T, Dq, Fq);
  wconvT<<<dim3(Dq / 64, Fq / 64), 256, 0, stream>>>(W2, W2T, Fq, Dq);
  phi_conv<<<512, 256, 0, stream>>>(phi, phiT);
  // 1) logits (BK=128) -> eT (exp, transposed), cbuf (row-softmax), xb (bf16 x copy)
  if (big)
    logits_mfma<true><<<dim3(Mq / 128, Bq), 256, 0, stream>>>(x, phiT, eT, cbuf, xb);
  else
    logits_mfma<false><<<dim3(Mq / 128, Bq), 256, 0, stream>>>(x, phiT, eT, cbuf, nullptr);
  // 2) token-softmax denominators
  colsum_rows<<<Bq * Nq, 256, 0, stream>>>(eT, cinv);
  // 3) xi partials (split-K 8, fragment-layout fp16) + reduce
  if (big) xi_mfma_xb<<<512, 256, 0, stream>>>(eT, xb, part);
  else     xi_mfma_f32<<<512, 256, 0, stream>>>(eT, x, part);
  xi_reduce<<<1024, 256, 0, stream>>>(part, cinv, xib);
  // 4) h = gelu(xi @ W1 + b1)
  gemm_tt<2, __bf16><<<dim3(8, 32, 1), 256, 0, stream>>>(
      xib, W1T, b1, h, Dq, Dq, Fq, 1024, 0L);
  // 5) yi partials = h @ W2 (split-K 4)
  gemm_tt<0, float><<<dim3(8, 8, 4), 256, 0, stream>>>(
      h, W2T, nullptr, g2part, Fq, Fq, Dq, 1024, 1048576L);
  // 6) reduce + b2 -> yiT bf16 [b][d][n]
  g2_reduce<<<4096, 256, 0, stream>>>(g2part, b2, yiT);
  // 7) y = c @ yi (staged-epilogue combine)
  combine_mfma<<<4096, 256, 0, stream>>>(cbuf, yiT, y);
}

// Round 14
// 365.291 us; speedup vs baseline: 1.0719x; 1.0719x over previous
//
#include <hip/hip_runtime.h>
#include <math.h>

#define Bq 8
#define Mq 8192
#define Dq 1024
#define Nq 128
#define Fq 4096

typedef __bf16 bf16x8 __attribute__((ext_vector_type(8)));
typedef float f32x4 __attribute__((ext_vector_type(4)));
union P4 { __bf16 h[4]; unsigned long long u; };
union H4 { short4 v; _Float16 h[4]; };
union B8 { int4 v; __bf16 h[8]; };
union U4 { ushort4 v; __bf16 h[4]; };

// swizzled LDS offsets: XOR byte-bits 4-6 with row&7 (365-µs-proven form)
__device__ __forceinline__ int swz128(int row, int bcol) {  // rows of 64 bf16 (128 B)
  return row * 128 + (bcol ^ ((row & 7) << 4));
}
__device__ __forceinline__ int swz256(int row, int bcol) {  // rows of 128 bf16 (256 B)
  return row * 256 + (bcol ^ ((row & 7) << 4));
}
// xi-local swizzle: folds row>>3 so 4-consecutive-row packed b128 writes spread banks
__device__ __forceinline__ int swzX(int row, int bcol) {
  return row * 128 + (bcol ^ ((((row & 7) ^ ((row >> 3) & 7))) << 4));
}

// ---------------- phi [1024 d][128 n] fp32 -> phiT [128 n][1024 d] bf16 ----------------
__global__ __launch_bounds__(256) void phi_conv(const float* __restrict__ src,
                                                __bf16* __restrict__ dst)
{
  int idx = blockIdx.x * 256 + threadIdx.x;   // 131072
  int d = idx >> 7, n = idx & 127;
  dst[(long)n * Dq + d] = (__bf16)src[idx];
}

// ---------------- transposing weight convert: src [R][C] fp32 -> dst [C][R] bf16 ----------------
__global__ __launch_bounds__(256) void wconvT(const float* __restrict__ src,
                                              __bf16* __restrict__ dst, int R, int C)
{
  __shared__ __bf16 tile[64][66];
  int c0 = blockIdx.x * 64, r0 = blockIdx.y * 64;
  int t = threadIdx.x;
  int row = t >> 2, cq = (t & 3) * 16;
  const float* S = src + (long)(r0 + row) * C + c0 + cq;
  #pragma unroll
  for (int q = 0; q < 4; ++q) {
    float4 v = *(const float4*)(S + q * 4);
    tile[cq + q * 4 + 0][row] = (__bf16)v.x;
    tile[cq + q * 4 + 1][row] = (__bf16)v.y;
    tile[cq + q * 4 + 2][row] = (__bf16)v.z;
    tile[cq + q * 4 + 3][row] = (__bf16)v.w;
  }
  __syncthreads();
  __bf16* D = dst + (long)(c0 + row) * R + r0 + cq;
  B8 o0, o1;
  #pragma unroll
  for (int e = 0; e < 8; ++e) { o0.h[e] = tile[row][cq + e]; o1.h[e] = tile[row][cq + 8 + e]; }
  *(int4*)(D) = o0.v;
  *(int4*)(D + 8) = o1.v;
}

// ---------------- logits = X @ phi via bf16 MFMA (128-m tiles, BK=64, grid 512) ----------------
// WXB: also emit xb bf16 [b][m][d]. Epilogue: cbuf row-softmax, eT = exp (transposed).
template<bool WXB>
__global__ __launch_bounds__(256) void logits_mfma(
    const float* __restrict__ x, const __bf16* __restrict__ phiT,
    __bf16* __restrict__ eT, __bf16* __restrict__ cbuf, __bf16* __restrict__ xb)
{
  __shared__ __align__(16) char sA[16384];  // x tile  [128 m][64 k]
  __shared__ __align__(16) char sP[16384];  // phiT    [128 n][64 k]
  int mt = blockIdx.x, b = blockIdx.y;
  int m0 = mt * 128;
  int t = threadIdx.x;
  int arow = t >> 4, ac4 = t & 15;
  int prow = t >> 1, pc = (t & 1) * 4;
  int w = t >> 6, l = t & 63, la = l & 15, lb = l >> 4;

  f32x4 zero = {0.f, 0.f, 0.f, 0.f};
  f32x4 acc[2][8];
  for (int i = 0; i < 2; ++i) for (int j = 0; j < 8; ++j) acc[i][j] = zero;

  for (int k0 = 0; k0 < Dq; k0 += 64) {
    #pragma unroll
    for (int i = 0; i < 8; ++i) {
      int row = arow + 16 * i;
      float4 v = *(const float4*)(x + ((long)b * Mq + m0 + row) * Dq + k0 + ac4 * 4);
      P4 p;
      p.h[0] = (__bf16)v.x; p.h[1] = (__bf16)v.y;
      p.h[2] = (__bf16)v.z; p.h[3] = (__bf16)v.w;
      *(unsigned long long*)(sA + swz128(row, 8 * ac4)) = p.u;
      if (WXB)
        *(unsigned long long*)(xb + ((long)b * Mq + m0 + row) * Dq + k0 + ac4 * 4) = p.u;
    }
    {
      const __bf16* Pp = phiT + (long)prow * Dq + k0 + pc * 8;
      #pragma unroll
      for (int q = 0; q < 4; ++q)
        *(int4*)(sP + swz128(prow, (pc + q) * 16)) = *(const int4*)(Pp + q * 8);
    }
    __syncthreads();
    #pragma unroll
    for (int sub = 0; sub < 2; ++sub) {
      int mbyte = sub * 64 + lb * 16;
      bf16x8 af0 = *(const bf16x8*)(sA + swz128(w * 32 + la, mbyte));
      bf16x8 af1 = *(const bf16x8*)(sA + swz128(w * 32 + 16 + la, mbyte));
      bf16x8 bv[8];
      #pragma unroll
      for (int j = 0; j < 8; ++j)
        bv[j] = *(const bf16x8*)(sP + swz128(j * 16 + la, mbyte));
      #pragma unroll
      for (int j = 0; j < 8; ++j) {
        acc[0][j] = __builtin_amdgcn_mfma_f32_16x16x32_bf16(af0, bv[j], acc[0][j], 0, 0, 0);
        acc[1][j] = __builtin_amdgcn_mfma_f32_16x16x32_bf16(af1, bv[j], acc[1][j], 0, 0, 0);
      }
    }
    __syncthreads();
  }
  // per-row (m) softmax denominators over 128 n (max-free, |l| <~ 6)
  float inv[2][4];
  #pragma unroll
  for (int i = 0; i < 2; ++i)
    #pragma unroll
    for (int r = 0; r < 4; ++r) {
      float s = 0.f;
      #pragma unroll
      for (int j = 0; j < 8; ++j) s += __expf(acc[i][j][r]);
      s += __shfl_xor(s, 1); s += __shfl_xor(s, 2);
      s += __shfl_xor(s, 4); s += __shfl_xor(s, 8);
      inv[i][r] = 1.0f / s;
    }
  __bf16* Cb = cbuf + ((long)b * Mq + m0) * Nq;
  __bf16* Eb = eT + (long)b * Nq * Mq + m0;
  #pragma unroll
  for (int i = 0; i < 2; ++i)
    #pragma unroll
    for (int j = 0; j < 8; ++j) {
      P4 p;
      #pragma unroll
      for (int r = 0; r < 4; ++r) {
        int row = w * 32 + i * 16 + lb * 4 + r;
        float e = __expf(acc[i][j][r]);
        p.h[r] = (__bf16)e;
        Cb[(long)row * Nq + j * 16 + la] = (__bf16)(e * inv[i][r]);
      }
      *(unsigned long long*)(Eb + (long)(j * 16 + la) * Mq + w * 32 + i * 16 + lb * 4) = p.u;
    }
}

// ---------------- cinv[b*128+n] = 1 / rowsum(eT) ----------------
__global__ __launch_bounds__(256) void colsum_rows(const __bf16* __restrict__ eT,
                                                   float* __restrict__ cinv)
{
  __shared__ float red[4];
  int r = blockIdx.x;
  int t = threadIdx.x;
  const __bf16* p = eT + (long)r * Mq;
  float s = 0.f;
  #pragma unroll
  for (int k = 0; k < 4; ++k) {
    B8 v; v.v = *(const int4*)(p + t * 8 + k * 2048);
    #pragma unroll
    for (int e = 0; e < 8; ++e) s += (float)v.h[e];
  }
  #pragma unroll
  for (int off = 32; off >= 1; off >>= 1) s += __shfl_down(s, off);
  if ((t & 63) == 0) red[t >> 6] = s;
  __syncthreads();
  if (t == 0) cinv[r] = 1.0f / (red[0] + red[1] + red[2] + red[3]);
}

// ---------------- xi partials from xb bf16: 128 n x 128 d per block, kc of 8 ----------------
__global__ __launch_bounds__(256) void xi_mfma_xb(
    const __bf16* __restrict__ eT, const __bf16* __restrict__ xb,
    _Float16* __restrict__ part)
{
  __shared__ __align__(16) char sD[16384];  // eT tile [128 n][64 m]
  __shared__ __align__(16) char sX[16384];  // xb^T tile [128 d][64 m]
  int lin = blockIdx.x;
  int wk = (lin & 7) * 64 + (lin >> 3);     // same-eT-chunk blocks -> same XCD
  int dts = wk & 7, kc = (wk >> 3) & 7, b = wk >> 6;
  int d0 = dts * 128;
  int t = threadIdx.x;
  int w = t >> 6, l = t & 63, la = l & 15, lb = l >> 4;
  int arow = t >> 1, ahalf = t & 1;
  const __bf16* Ep0 = eT + ((long)b * Nq + arow) * Mq + kc * 1024 + ahalf * 32;
  int bmb = (w * 2 + (l >> 5)) * 8;
  int bd  = (l & 31) * 4;
  const __bf16* Xp0 = xb + ((long)b * Mq + kc * 1024 + bmb) * Dq + d0 + bd;

  f32x4 zero = {0.f, 0.f, 0.f, 0.f};
  f32x4 acc[2][8];
  for (int i = 0; i < 2; ++i) for (int j = 0; j < 8; ++j) acc[i][j] = zero;

  int4 ar[4];
  U4 br[8];
  #pragma unroll
  for (int q = 0; q < 4; ++q) ar[q] = *(const int4*)(Ep0 + q * 8);
  #pragma unroll
  for (int k = 0; k < 8; ++k) br[k].v = *(const ushort4*)(Xp0 + (long)k * Dq);
  #pragma unroll
  for (int q = 0; q < 4; ++q) *(int4*)(sD + swzX(arow, ahalf * 64 + q * 16)) = ar[q];
  #pragma unroll
  for (int q = 0; q < 4; ++q) {
    B8 o;
    #pragma unroll
    for (int k = 0; k < 8; ++k) o.h[k] = br[k].h[q];
    *(int4*)(sX + swzX(bd + q, 2 * bmb)) = o.v;
  }

  for (int it = 0; it < 16; ++it) {
    __syncthreads();
    if (it < 15) {
      #pragma unroll
      for (int q = 0; q < 4; ++q) ar[q] = *(const int4*)(Ep0 + (it + 1) * 64 + q * 8);
      #pragma unroll
      for (int k = 0; k < 8; ++k)
        br[k].v = *(const ushort4*)(Xp0 + ((long)(it + 1) * 64 + k) * Dq);
    }
    #pragma unroll
    for (int sub = 0; sub < 2; ++sub) {
      int mbyte = sub * 64 + lb * 16;
      bf16x8 af0 = *(const bf16x8*)(sD + swzX(w * 32 + la, mbyte));
      bf16x8 af1 = *(const bf16x8*)(sD + swzX(w * 32 + 16 + la, mbyte));
      #pragma unroll
      for (int j = 0; j < 8; ++j) {
        bf16x8 bv = *(const bf16x8*)(sX + swzX(j * 16 + la, mbyte));
        acc[0][j] = __builtin_amdgcn_mfma_f32_16x16x32_bf16(af0, bv, acc[0][j], 0, 0, 0);
        acc[1][j] = __builtin_amdgcn_mfma_f32_16x16x32_bf16(af1, bv, acc[1][j], 0, 0, 0);
      }
    }
    __syncthreads();
    if (it < 15) {
      #pragma unroll
      for (int q = 0; q < 4; ++q) *(int4*)(sD + swzX(arow, ahalf * 64 + q * 16)) = ar[q];
      #pragma unroll
      for (int q = 0; q < 4; ++q) {
        B8 o;
        #pragma unroll
        for (int k = 0; k < 8; ++k) o.h[k] = br[k].h[q];
        *(int4*)(sX + swzX(bd + q, 2 * bmb)) = o.v;
      }
    }
  }
  _Float16* P = part + (((long)kc * Bq + b) * 8 + dts) * 16384;
  #pragma unroll
  for (int i = 0; i < 2; ++i)
    #pragma unroll
    for (int j = 0; j < 8; ++j) {
      H4 o;
      #pragma unroll
      for (int r = 0; r < 4; ++r) o.h[r] = (_Float16)acc[i][j][r];
      *(short4*)(P + ((w * 16 + i * 8 + j) * 64 + l) * 4) = o.v;
    }
}

// ---------------- xi fallback (fp32 x) for small ws ----------------
__global__ __launch_bounds__(256) void xi_mfma_f32(
    const __bf16* __restrict__ eT, const float* __restrict__ x,
    _Float16* __restrict__ part)
{
  __shared__ __align__(16) char sD[16384];
  __shared__ __align__(16) char sX[16384];
  int lin = blockIdx.x;
  int wk = (lin & 7) * 64 + (lin >> 3);
  int dts = wk & 7, kc = (wk >> 3) & 7, b = wk >> 6;
  int d0 = dts * 128;
  int t = threadIdx.x;
  int w = t >> 6, l = t & 63, la = l & 15, lb = l >> 4;
  int arow = t >> 1, ahalf = t & 1;
  const __bf16* Ep0 = eT + ((long)b * Nq + arow) * Mq + kc * 1024 + ahalf * 32;
  int bmb = (w * 2 + (l >> 5)) * 8;
  int bd  = (l & 31) * 4;
  const float* Xp0 = x + ((long)b * Mq + kc * 1024 + bmb) * Dq + d0 + bd;

  f32x4 zero = {0.f, 0.f, 0.f, 0.f};
  f32x4 acc[2][8];
  for (int i = 0; i < 2; ++i) for (int j = 0; j < 8; ++j) acc[i][j] = zero;

  int4 ar[4];
  float br[8][4];
  #pragma unroll
  for (int q = 0; q < 4; ++q) ar[q] = *(const int4*)(Ep0 + q * 8);
  #pragma unroll
  for (int k = 0; k < 8; ++k) *(float4*)br[k] = *(const float4*)(Xp0 + (long)k * Dq);
  #pragma unroll
  for (int q = 0; q < 4; ++q) *(int4*)(sD + swzX(arow, ahalf * 64 + q * 16)) = ar[q];
  #pragma unroll
  for (int q = 0; q < 4; ++q) {
    B8 o;
    #pragma unroll
    for (int k = 0; k < 8; ++k) o.h[k] = (__bf16)br[k][q];
    *(int4*)(sX + swzX(bd + q, 2 * bmb)) = o.v;
  }
  for (int it = 0; it < 16; ++it) {
    __syncthreads();
    if (it < 15) {
      #pragma unroll
      for (int q = 0; q < 4; ++q) ar[q] = *(const int4*)(Ep0 + (it + 1) * 64 + q * 8);
      #pragma unroll
      for (int k = 0; k < 8; ++k)
        *(float4*)br[k] = *(const float4*)(Xp0 + ((long)(it + 1) * 64 + k) * Dq);
    }
    #pragma unroll
    for (int sub = 0; sub < 2; ++sub) {
      int mbyte = sub * 64 + lb * 16;
      bf16x8 af0 = *(const bf16x8*)(sD + swzX(w * 32 + la, mbyte));
      bf16x8 af1 = *(const bf16x8*)(sD + swzX(w * 32 + 16 + la, mbyte));
      #pragma unroll
      for (int j = 0; j < 8; ++j) {
        bf16x8 bv = *(const bf16x8*)(sX + swzX(j * 16 + la, mbyte));
        acc[0][j] = __builtin_amdgcn_mfma_f32_16x16x32_bf16(af0, bv, acc[0][j], 0, 0, 0);
        acc[1][j] = __builtin_amdgcn_mfma_f32_16x16x32_bf16(af1, bv, acc[1][j], 0, 0, 0);
      }
    }
    __syncthreads();
    if (it < 15) {
      #pragma unroll
      for (int q = 0; q < 4; ++q) *(int4*)(sD + swzX(arow, ahalf * 64 + q * 16)) = ar[q];
      #pragma unroll
      for (int q = 0; q < 4; ++q) {
        B8 o;
        #pragma unroll
        for (int k = 0; k < 8; ++k) o.h[k] = (__bf16)br[k][q];
        *(int4*)(sX + swzX(bd + q, 2 * bmb)) = o.v;
      }
    }
  }
  _Float16* P = part + (((long)kc * Bq + b) * 8 + dts) * 16384;
  #pragma unroll
  for (int i = 0; i < 2; ++i)
    #pragma unroll
    for (int j = 0; j < 8; ++j) {
      H4 o;
      #pragma unroll
      for (int r = 0; r < 4; ++r) o.h[r] = (_Float16)acc[i][j][r];
      *(short4*)(P + ((w * 16 + i * 8 + j) * 64 + l) * 4) = o.v;
    }
}

// ---------------- xi reduce (fragment layout): xib[n][d] = bf16(cinv * sum_kc) ----------------
__global__ __launch_bounds__(256) void xi_reduce(const _Float16* __restrict__ part,
    const float* __restrict__ cinv, __bf16* __restrict__ xib)
{
  int s = blockIdx.x * 256 + threadIdx.x;   // 262144 fragment slots (4 vals each)
  int l = s & 63, j = (s >> 6) & 7, i = (s >> 9) & 1;
  int w = (s >> 10) & 3, dts = (s >> 12) & 7, b = s >> 15;
  const _Float16* p = part + ((long)b * 8 + dts) * 16384 + ((w * 16 + i * 8 + j) * 64 + l) * 4;
  float sum[4] = {};
  #pragma unroll
  for (int kc = 0; kc < 8; ++kc) {
    H4 v; v.v = *(const short4*)(p + (long)kc * 1048576);
    #pragma unroll
    for (int r = 0; r < 4; ++r) sum[r] += (float)v.h[r];
  }
  int lb = l >> 4, la = l & 15;
  int nbase = w * 32 + i * 16 + lb * 4;
  int d = dts * 128 + j * 16 + la;
  #pragma unroll
  for (int r = 0; r < 4; ++r) {
    int n = b * 128 + nbase + r;
    xib[(long)n * Dq + d] = (__bf16)(sum[r] * cinv[n]);
  }
}

// ---------------- bf16 MFMA GEMM, BOTH operands k-contiguous: A[m][k], BT[n][k] ----------------
template<int EPI, typename OT>
__global__ __launch_bounds__(256) void gemm_tt(const __bf16* __restrict__ A,
    const __bf16* __restrict__ BT, const float* __restrict__ bias,
    OT* __restrict__ C, int lda, int ldb, int ldc, int kLen, long strideCz)
{
  __shared__ __align__(16) char sA[16384];
  __shared__ __align__(16) char sB[16384];
  int m0 = blockIdx.x * 128, n0 = blockIdx.y * 128;
  int kbase = blockIdx.z * kLen;
  C += (long)blockIdx.z * strideCz;
  int t = threadIdx.x;
  int w = t >> 6, l = t & 63, la = l & 15, lb = l >> 4;

  f32x4 zero = {0.f, 0.f, 0.f, 0.f};
  f32x4 acc[2][8];
  for (int i = 0; i < 2; ++i) for (int j = 0; j < 8; ++j) acc[i][j] = zero;

  for (int kt = 0; kt < kLen; kt += 64) {
    int kp = kbase + kt;
    #pragma unroll
    for (int s = 0; s < 4; ++s) {
      int idx = t + 256 * s;
      int row = idx >> 3, c8 = idx & 7;
      *(int4*)(sA + swz128(row, c8 * 16)) =
          *(const int4*)(A + (long)(m0 + row) * lda + kp + c8 * 8);
      *(int4*)(sB + swz128(row, c8 * 16)) =
          *(const int4*)(BT + (long)(n0 + row) * ldb + kp + c8 * 8);
    }
    __syncthreads();
    #pragma unroll
    for (int sub = 0; sub < 2; ++sub) {
      int mbyte = sub * 64 + lb * 16;
      bf16x8 af0 = *(const bf16x8*)(sA + swz128(w * 32 + la, mbyte));
      bf16x8 af1 = *(const bf16x8*)(sA + swz128(w * 32 + 16 + la, mbyte));
      bf16x8 bv[8];
      #pragma unroll
      for (int j = 0; j < 8; ++j)
        bv[j] = *(const bf16x8*)(sB + swz128(j * 16 + la, mbyte));
      #pragma unroll
      for (int j = 0; j < 8; ++j) {
        acc[0][j] = __builtin_amdgcn_mfma_f32_16x16x32_bf16(af0, bv[j], acc[0][j], 0, 0, 0);
        acc[1][j] = __builtin_amdgcn_mfma_f32_16x16x32_bf16(af1, bv[j], acc[1][j], 0, 0, 0);
      }
    }
    __syncthreads();
  }
  #pragma unroll
  for (int i = 0; i < 2; ++i)
    #pragma unroll
    for (int j = 0; j < 8; ++j)
      #pragma unroll
      for (int r = 0; r < 4; ++r) {
        int row = m0 + w * 32 + i * 16 + lb * 4 + r;
        int colg = n0 + j * 16 + la;
        float v = acc[i][j][r];
        if (EPI == 2) {
          v += bias[colg];
          v = 0.5f * v * (1.0f + erff(v * 0.70710678118654752f));
        }
        C[(long)row * ldc + colg] = (OT)v;
      }
}

// ---------------- G2 reduce: yiT[b][d][n] = bf16(sum_kc part + b2[d]) ----------------
__global__ __launch_bounds__(256) void g2_reduce(const float* __restrict__ part,
    const float* __restrict__ b2, __bf16* __restrict__ yiT)
{
  long idx = (long)blockIdx.x * 256 + threadIdx.x;
  int row = (int)(idx >> 10);
  int d = (int)(idx & 1023);
  float s = part[idx] + part[idx + 1048576] + part[idx + 2097152] + part[idx + 3145728] + b2[d];
  int b = row >> 7, n = row & 127;
  yiT[((long)b * Dq + d) * Nq + n] = (__bf16)s;
}

// ---------------- combine: y[b,m,d] = sum_n cbuf[m,n] * yiT[d,n] ----------------
// LDS-staged y epilogue: acc -> 64KB LDS (xor-swizzled) -> 512B-run coalesced stores
__global__ __launch_bounds__(256) void combine_mfma(const __bf16* __restrict__ cbuf,
    const __bf16* __restrict__ yiT, float* __restrict__ y)
{
  __shared__ __align__(16) char smem[65536];
  char* sC = smem;            // c  [128 m][128 n]
  char* sY = smem + 32768;    // yi [128 d][128 n]
  int lin = blockIdx.x;
  int wk = (lin & 7) * 512 + (lin >> 3);
  int dt = wk & 7, mt = (wk >> 3) & 63, b = wk >> 9;
  int m0 = mt * 128, d0 = dt * 128;
  int t = threadIdx.x;
  #pragma unroll
  for (int s = 0; s < 8; ++s) {
    int idx = t + 256 * s;
    int row = idx >> 4, c16 = idx & 15;
    *(int4*)(sC + swz256(row, c16 * 16)) =
        *(const int4*)(cbuf + ((long)b * Mq + m0 + row) * Nq + c16 * 8);
    *(int4*)(sY + swz256(row, c16 * 16)) =
        *(const int4*)(yiT + ((long)b * Dq + d0 + row) * Nq + c16 * 8);
  }
  __syncthreads();
  int w = t >> 6, l = t & 63, la = l & 15, lb = l >> 4;
  f32x4 zero = {0.f, 0.f, 0.f, 0.f};
  f32x4 acc[2][8];
  for (int i = 0; i < 2; ++i) for (int j = 0; j < 8; ++j) acc[i][j] = zero;
  #pragma unroll
  for (int sub = 0; sub < 4; ++sub) {
    int mbyte = sub * 64 + lb * 16;
    bf16x8 af0 = *(const bf16x8*)(sC + swz256(w * 32 + la, mbyte));
    bf16x8 af1 = *(const bf16x8*)(sC + swz256(w * 32 + 16 + la, mbyte));
    #pragma unroll
    for (int j = 0; j < 8; ++j) {
      bf16x8 bv = *(const bf16x8*)(sY + swz256(j * 16 + la, mbyte));
      acc[0][j] = __builtin_amdgcn_mfma_f32_16x16x32_bf16(af0, bv, acc[0][j], 0, 0, 0);
      acc[1][j] = __builtin_amdgcn_mfma_f32_16x16x32_bf16(af1, bv, acc[1][j], 0, 0, 0);
    }
  }
  // stage acc through LDS for long-run y stores
  __syncthreads();
  float* sF = (float*)smem;   // y tile [128 m][128 d], col ^ (((row>>2)&3)<<3)
  #pragma unroll
  for (int i = 0; i < 2; ++i)
    #pragma unroll
    for (int j = 0; j < 8; ++j)
      #pragma unroll
      for (int r = 0; r < 4; ++r) {
        int row = w * 32 + i * 16 + lb * 4 + r;
        sF[row * 128 + ((j * 16 + la) ^ (lb << 3))] = acc[i][j][r];
      }
  __syncthreads();
  int orow = t >> 5, oc = (t & 31) * 4;   // 8 rows/pass x 32 lanes -> 512B runs
  #pragma unroll
  for (int p = 0; p < 16; ++p) {
    int row = orow + 8 * p;
    int xorv = ((row >> 2) & 3) << 3;
    float4 v = *(const float4*)&sF[row * 128 + (oc ^ xorv)];
    *(float4*)(y + ((long)b * Mq + m0 + row) * Dq + d0 + oc) = v;
  }
}

extern "C" void kernel_launch(void* const* d_in, const int* in_sizes, int n_in,
                              void* d_out, int out_size, void* d_ws, size_t ws_size,
                              hipStream_t stream) {
  const float* x   = (const float*)d_in[0];
  const float* phi = (const float*)d_in[1];
  const float* W1  = (const float*)d_in[2];
  const float* b1  = (const float*)d_in[3];
  const float* W2  = (const float*)d_in[4];
  const float* b2  = (const float*)d_in[5];
  float* y = (float*)d_out;

  char* W = (char*)d_ws;
  __bf16*   cbuf   = (__bf16*)W;                      // 16 MB
  __bf16*   eT     = (__bf16*)(W + 16777216);         // 16 MB  [b][n][m]
  __bf16*   h      = eT;                              // aliases eT (dead after xi)
  _Float16* part   = (_Float16*)(W + 33554432);       // 16 MB fp16 fragment-layout
  float*    g2part = (float*)(W + 33554432);          // aliases part (dead after xi_reduce)
  __bf16*   W1T    = (__bf16*)(W + 50331648);         // 8 MB  [f][d]
  __bf16*   W2T    = (__bf16*)(W + 58720256);         // 8 MB  [d][f]
  __bf16*   xib    = (__bf16*)(W + 67108864);         // 2 MB
  __bf16*   yiT    = (__bf16*)(W + 69206016);         // 2 MB
  float*    cinv   = (float*)(W + 71303168);          // 4 KB
  __bf16*   phiT   = (__bf16*)(W + 72351744);         // 256 KB [n][d]
  __bf16*   xb     = (__bf16*)(W + 73400320);         // 128 MB [b][m][d] bf16 (optional)
  bool big = ws_size >= 207618048ull;                 // 70 MB base + 128 MB xb

  // 0) weights -> transposed bf16; phi -> transposed bf16
  wconvT<<<dim3(Fq / 64, Dq / 64), 256, 0, stream>>>(W1, W1T, Dq, Fq);
  wconvT<<<dim3(Dq / 64, Fq / 64), 256, 0, stream>>>(W2, W2T, Fq, Dq);
  phi_conv<<<512, 256, 0, stream>>>(phi, phiT);
  // 1) logits (BK=64) -> eT (exp, transposed), cbuf (row-softmax), xb (bf16 x copy)
  if (big)
    logits_mfma<true><<<dim3(Mq / 128, Bq), 256, 0, stream>>>(x, phiT, eT, cbuf, xb);
  else
    logits_mfma<false><<<dim3(Mq / 128, Bq), 256, 0, stream>>>(x, phiT, eT, cbuf, nullptr);
  // 2) token-softmax denominators
  colsum_rows<<<Bq * Nq, 256, 0, stream>>>(eT, cinv);
  // 3) xi partials (split-K 8, fragment-layout fp16) + reduce
  if (big) xi_mfma_xb<<<512, 256, 0, stream>>>(eT, xb, part);
  else     xi_mfma_f32<<<512, 256, 0, stream>>>(eT, x, part);
  xi_reduce<<<1024, 256, 0, stream>>>(part, cinv, xib);
  // 4) h = gelu(xi @ W1 + b1)
  gemm_tt<2, __bf16><<<dim3(8, 32, 1), 256, 0, stream>>>(
      xib, W1T, b1, h, Dq, Dq, Fq, 1024, 0L);
  // 5) yi partials = h @ W2 (split-K 4)
  gemm_tt<0, float><<<dim3(8, 8, 4), 256, 0, stream>>>(
      h, W2T, nullptr, g2part, Fq, Fq, Dq, 1024, 1048576L);
  // 6) reduce + b2 -> yiT bf16 [b][d][n]
  g2_reduce<<<4096, 256, 0, stream>>>(g2part, b2, yiT);
  // 7) y = c @ yi (staged-epilogue combine)
  combine_mfma<<<4096, 256, 0, stream>>>(cbuf, yiT, y);
}